// Round 14
// baseline (89.843 us; speedup 1.0000x reference)
//
#include <hip/hip_runtime.h>

typedef __attribute__((ext_vector_type(8))) _Float16 f16x8;
typedef __attribute__((ext_vector_type(4))) _Float16 f16x4;
typedef __attribute__((ext_vector_type(4))) float   f32x4;

#define BATCH 16384
#define NFEAT 512
#define NCLS  1000
#define NLEAF 256
#define NINT  255
#define LDP   72    // staging LDS row stride (f16), 144B
#define PSTR  257   // P LDS row stride (f32)

// ---- convert gate_w (255x512) -> f16 padded to 256x512 (row 255 = 0) ----
__global__ __launch_bounds__(256) void cvt_gw(const float4* __restrict__ in,
                                              f16x4* __restrict__ out) {
  int i = blockIdx.x * 256 + threadIdx.x;
  int row = i >> 7;
  f16x4 o;
  if (row < NINT) {
    float4 v = in[i];
    o[0] = (_Float16)v.x; o[1] = (_Float16)v.y;
    o[2] = (_Float16)v.z; o[3] = (_Float16)v.w;
  } else {
    o[0] = o[1] = o[2] = o[3] = (_Float16)0.f;
  }
  out[i] = o;
}

// ---- softmax of leaf_logits rows -> distF in MFMA-fragment-swizzled layout ----
// (class c, leaf l) at ((c>>4)*8 + (l>>5))*512 + ((l>>3&3)*16 + (c&15))*8 + (l&7)
__global__ __launch_bounds__(256) void softmax_t(const float* __restrict__ L,
                                                 _Float16* __restrict__ distF) {
  __shared__ float red[4];
  const int l = blockIdx.x, t = threadIdx.x;
  const int wave = t >> 6, lane = t & 63;
  const int kt = l >> 5, lhi_l = (l >> 3) & 3, jj = l & 7;
  float v[4];
  const bool live = t < 250;
  if (live) {
    float4 f = *(const float4*)&L[(size_t)l * NCLS + t * 4];
    v[0] = f.x; v[1] = f.y; v[2] = f.z; v[3] = f.w;
  } else {
    v[0] = v[1] = v[2] = v[3] = -1e30f;
  }
  float mx = fmaxf(fmaxf(v[0], v[1]), fmaxf(v[2], v[3]));
#pragma unroll
  for (int s = 32; s; s >>= 1) mx = fmaxf(mx, __shfl_xor(mx, s));
  if (lane == 0) red[wave] = mx;
  __syncthreads();
  mx = fmaxf(fmaxf(red[0], red[1]), fmaxf(red[2], red[3]));
  __syncthreads();
  float e[4], sum = 0.f;
#pragma unroll
  for (int i = 0; i < 4; ++i) { e[i] = __expf(v[i] - mx); sum += e[i]; }
  if (!live) { e[0] = e[1] = e[2] = e[3] = 0.f; sum = 0.f; }
#pragma unroll
  for (int s = 32; s; s >>= 1) sum += __shfl_xor(sum, s);
  if (lane == 0) red[wave] = sum;
  __syncthreads();
  sum = red[0] + red[1] + red[2] + red[3];
  float inv = 1.f / sum;
#pragma unroll
  for (int i = 0; i < 4; ++i) {
    int c = t * 4 + i;
    float val = live ? e[i] * inv : 0.f;
    int c16 = c >> 4, ln = c & 15;
    size_t idx = (((size_t)(c16 * 8 + kt)) * 64 + lhi_l * 16 + ln) * 8 + jj;
    distF[idx] = (_Float16)val;
  }
}

// ---- kernel 1: gemm1 + sigmoid + tree -> muF (global, fragment layout) ----
// BM=32, 512 blocks, 512 threads (8 waves), LDS 41.5 KB.
// launch_bounds(512,2): allocator ceiling ~256 VGPR -> no spills (R12-proven config);
// actual VGPR ~88 still runs 2 blocks/CU (4 waves/SIMD x 88 = 352 <= 512 pool).
__global__ __launch_bounds__(512, 2)
void g1mu(const float* __restrict__ x, const _Float16* __restrict__ gwh,
          const float* __restrict__ gb, _Float16* __restrict__ muFg) {
  __shared__ union {
    struct { _Float16 A[32 * LDP]; _Float16 B[256 * LDP]; } s;  // 41,472 B
    float P[32 * PSTR];                                         // 32,896 B
  } sm;

  const int tid  = threadIdx.x;
  const int wave = tid >> 6, lane = tid & 63;
  const int ln15 = lane & 15, lhi = lane >> 4;
  const int wr = wave >> 2, wc = wave & 3;      // 2x4 waves: 16 rows x 64 cols
  const int r0 = blockIdx.x * 32;

  float bias_[4];
#pragma unroll
  for (int n = 0; n < 4; ++n) {
    int col = wc * 64 + n * 16 + ln15;
    bias_[n] = (col < NINT) ? gb[col] : 0.f;
  }

  // ---------------- phase 1: logits = x @ gwh^T (1-deep prefetch, spill-free) ----------------
  f32x4 acc1[4] = {};
  const int arow = tid >> 4, acol = (tid & 15) * 4;  // A: 1 float4/thread
  const int brow = tid >> 3, bcol = (tid & 7) * 8;   // B: 4 uint4/thread

  float4 pa;
  uint4  pb[4];

#define P1_LOAD(k0)                                                              \
  {                                                                              \
    pa = *(const float4*)&x[(size_t)(r0 + arow) * NFEAT + (k0) + acol];          \
    _Pragma("unroll")                                                            \
    for (int i = 0; i < 4; ++i)                                                  \
      pb[i] = *(const uint4*)&gwh[(size_t)(i * 64 + brow) * NFEAT + (k0) + bcol];\
  }
#define P1_WRITE()                                                               \
  {                                                                              \
    f16x4 h;                                                                     \
    h[0] = (_Float16)pa.x; h[1] = (_Float16)pa.y;                                \
    h[2] = (_Float16)pa.z; h[3] = (_Float16)pa.w;                                \
    *(f16x4*)&sm.s.A[arow * LDP + acol] = h;                                     \
    _Pragma("unroll")                                                            \
    for (int i = 0; i < 4; ++i)                                                  \
      *(uint4*)&sm.s.B[(i * 64 + brow) * LDP + bcol] = pb[i];                    \
  }

  P1_LOAD(0);
  for (int k = 0; k < NFEAT / 64; ++k) {
    P1_WRITE();
    __syncthreads();
    if (k < NFEAT / 64 - 1) P1_LOAD((k + 1) * 64);
#pragma unroll
    for (int kk = 0; kk < 2; ++kk) {
      f16x8 a, b[4];
      a = *(const f16x8*)&sm.s.A[(wr * 16 + ln15) * LDP + kk * 32 + lhi * 8];
#pragma unroll
      for (int n = 0; n < 4; ++n)
        b[n] = *(const f16x8*)&sm.s.B[(wc * 64 + n * 16 + ln15) * LDP + kk * 32 + lhi * 8];
#pragma unroll
      for (int n = 0; n < 4; ++n)
        acc1[n] = __builtin_amdgcn_mfma_f32_16x16x32_f16(a, b[n], acc1[n], 0, 0, 0);
    }
    __syncthreads();
  }

  // ---------------- phase 2a: sigmoid -> P (LDS) ----------------
#pragma unroll
  for (int n = 0; n < 4; ++n) {
    int col = wc * 64 + n * 16 + ln15;
#pragma unroll
    for (int j = 0; j < 4; ++j) {
      int rl = wr * 16 + lhi * 4 + j;
      float v = acc1[n][j] + bias_[n];
      sm.P[rl * PSTR + col] = 1.f / (1.f + __expf(-v));
    }
  }
  __syncthreads();

  // ---------------- phase 2b: tree product -> muFg (global, fragment layout) ----------------
  const int lf   = lane * 4;
  const int g_hi = lane >> 3;            // k-tile index (leaf>>5)
  const int sub  = ((lane >> 1) & 3) * 16;
  const int j4   = (lane & 1) * 4;
#pragma unroll
  for (int rr = 0; rr < 4; ++rr) {
    int row = wave * 4 + rr;             // 8 waves x 4 = 32 rows
    const float* p = &sm.P[row * PSTR];
    float pre = 1.f;
#pragma unroll
    for (int d = 0; d < 6; ++d) {
      int node = (1 << d) - 1 + (lf >> (8 - d));
      int bit  = (lf >> (7 - d)) & 1;
      float g = p[node];
      pre *= bit ? g : (1.f - g);
    }
    float g6  = p[63 + lane];
    float g7a = p[127 + 2 * lane];
    float g7b = p[128 + 2 * lane];
    f16x4 o;
    o[0] = (_Float16)(pre * (1.f - g6) * (1.f - g7a));
    o[1] = (_Float16)(pre * (1.f - g6) * g7a);
    o[2] = (_Float16)(pre * g6 * (1.f - g7b));
    o[3] = (_Float16)(pre * g6 * g7b);
    int row_g = r0 + row;
    size_t idx = (((size_t)(row_g >> 4) * 8 + g_hi) * 64 + sub + (row_g & 15)) * 8 + j4;
    *(f16x4*)&muFg[idx] = o;
  }
#undef P1_LOAD
#undef P1_WRITE
}

// ---- kernel 2: out = mu @ dist^T. No LDS, fragment loads, high occupancy ----
// grid (256 row-blocks x 4 col-strips), 256 threads (4 waves).
__global__ __launch_bounds__(256)
void g2(const _Float16* __restrict__ muFg, const _Float16* __restrict__ distF,
        float* __restrict__ out) {
  const int tid  = threadIdx.x;
  const int wave = tid >> 6, lane = tid & 63;
  const int ln15 = lane & 15, lhi = lane >> 4;
  const int row16 = blockIdx.x * 4 + wave;     // 16-row group
  const int cs    = blockIdx.y;                // 256-col strip

  f16x8 aa[8];
#pragma unroll
  for (int kk = 0; kk < 8; ++kk)               // 1KB contiguous per load
    aa[kk] = *(const f16x8*)&muFg[(((size_t)row16 * 8 + kk) * 64 + lane) * 8];

  const int rb = row16 * 16 + lhi * 4;
  for (int ct = 0; ct < 16; ++ct) {
    const int c16 = cs * 16 + ct;
    f32x4 acc = {};
#pragma unroll
    for (int kk = 0; kk < 8; ++kk) {
      f16x8 bb = *(const f16x8*)&distF[(((size_t)c16 * 8 + kk) * 64 + lane) * 8];
      acc = __builtin_amdgcn_mfma_f32_16x16x32_f16(aa[kk], bb, acc, 0, 0, 0);
    }
    const int col = c16 * 16 + ln15;
    if (col < NCLS) {
#pragma unroll
      for (int j = 0; j < 4; ++j)
        out[(size_t)(rb + j) * NCLS + col] = acc[j];
    }
  }
}

extern "C" void kernel_launch(void* const* d_in, const int* in_sizes, int n_in,
                              void* d_out, int out_size, void* d_ws, size_t ws_size,
                              hipStream_t stream) {
  const float* x  = (const float*)d_in[0];   // 16384x512
  const float* gw = (const float*)d_in[1];   // 255x512
  const float* gb = (const float*)d_in[2];   // 255
  const float* ll = (const float*)d_in[3];   // 256x1000
  float* out = (float*)d_out;                // 16384x1000
  char* ws = (char*)d_ws;

  _Float16* gwh   = (_Float16*)(ws);             // 262,144 B
  _Float16* distF = (_Float16*)(ws + 262144);    // 524,288 B
  _Float16* muFg  = (_Float16*)(ws + 786432);    // 8,388,608 B (fragment layout)

  cvt_gw   <<<128, 256, 0, stream>>>((const float4*)gw, (f16x4*)gwh);
  softmax_t<<<256, 256, 0, stream>>>(ll, distF);
  g1mu     <<<BATCH / 32, 512, 0, stream>>>(x, gwh, gb, muFg);
  g2       <<<dim3(BATCH / 64, 4), 256, 0, stream>>>(muFg, distF, out);
}

// Round 15
// 60.754 us; speedup vs baseline: 1.4788x; 1.4788x over previous
//
#include <hip/hip_runtime.h>

typedef __attribute__((ext_vector_type(8))) _Float16 f16x8;
typedef __attribute__((ext_vector_type(4))) _Float16 f16x4;
typedef __attribute__((ext_vector_type(4))) float   f32x4;

#define BATCH 16384
#define NFEAT 512
#define NCLS  1000
#define NLEAF 256
#define NINT  255
#define LDP   72    // A-staging LDS row stride (f16), 144B
#define PSTR  257   // P LDS row stride (f32)

// ---- gate_w (255x512) f32 -> gwF f16 in MFMA-B-fragment layout, padded to 256 rows ----
// fragment pair p = c16*16 + ks (c16: 16-col group, ks: 32-k slice);
// gwF[(p*64 + lane)*8 + j] = W[c16*16 + (lane&15)][ks*32 + (lane>>4)*8 + j]
__global__ __launch_bounds__(64) void cvt_gw(const float* __restrict__ gw,
                                             _Float16* __restrict__ gwF) {
  const int p = blockIdx.x;             // 256 pairs
  const int lane = threadIdx.x;         // 64
  const int c = (p >> 4) * 16 + (lane & 15);
  const int k0 = (p & 15) * 32 + (lane >> 4) * 8;
  f16x8 o = {};
  if (c < NINT) {
    float4 v0 = *(const float4*)&gw[(size_t)c * NFEAT + k0];
    float4 v1 = *(const float4*)&gw[(size_t)c * NFEAT + k0 + 4];
    o[0] = (_Float16)v0.x; o[1] = (_Float16)v0.y;
    o[2] = (_Float16)v0.z; o[3] = (_Float16)v0.w;
    o[4] = (_Float16)v1.x; o[5] = (_Float16)v1.y;
    o[6] = (_Float16)v1.z; o[7] = (_Float16)v1.w;
  }
  *(f16x8*)&gwF[((size_t)p * 64 + lane) * 8] = o;   // 16B/lane contiguous
}

// ---- softmax of leaf_logits rows -> distF in MFMA-fragment-swizzled layout ----
// (class c, leaf l) at ((c>>4)*8 + (l>>5))*512 + ((l>>3&3)*16 + (c&15))*8 + (l&7)
__global__ __launch_bounds__(256) void softmax_t(const float* __restrict__ L,
                                                 _Float16* __restrict__ distF) {
  __shared__ float red[4];
  const int l = blockIdx.x, t = threadIdx.x;
  const int wave = t >> 6, lane = t & 63;
  const int kt = l >> 5, lhi_l = (l >> 3) & 3, jj = l & 7;
  float v[4];
  const bool live = t < 250;
  if (live) {
    float4 f = *(const float4*)&L[(size_t)l * NCLS + t * 4];
    v[0] = f.x; v[1] = f.y; v[2] = f.z; v[3] = f.w;
  } else {
    v[0] = v[1] = v[2] = v[3] = -1e30f;
  }
  float mx = fmaxf(fmaxf(v[0], v[1]), fmaxf(v[2], v[3]));
#pragma unroll
  for (int s = 32; s; s >>= 1) mx = fmaxf(mx, __shfl_xor(mx, s));
  if (lane == 0) red[wave] = mx;
  __syncthreads();
  mx = fmaxf(fmaxf(red[0], red[1]), fmaxf(red[2], red[3]));
  __syncthreads();
  float e[4], sum = 0.f;
#pragma unroll
  for (int i = 0; i < 4; ++i) { e[i] = __expf(v[i] - mx); sum += e[i]; }
  if (!live) { e[0] = e[1] = e[2] = e[3] = 0.f; sum = 0.f; }
#pragma unroll
  for (int s = 32; s; s >>= 1) sum += __shfl_xor(sum, s);
  if (lane == 0) red[wave] = sum;
  __syncthreads();
  sum = red[0] + red[1] + red[2] + red[3];
  float inv = 1.f / sum;
#pragma unroll
  for (int i = 0; i < 4; ++i) {
    int c = t * 4 + i;
    float val = live ? e[i] * inv : 0.f;
    int c16 = c >> 4, ln = c & 15;
    size_t idx = (((size_t)(c16 * 8 + kt)) * 64 + lhi_l * 16 + ln) * 8 + jj;
    distF[idx] = (_Float16)val;
  }
}

// ---- kernel 1: gemm1 + sigmoid + tree -> muFg (global, fragment layout) ----
// BM=32, 512 blocks, 512 threads (8 waves, 2x4). B read fragment-direct from L2 (gwF):
// no pb staging regs, no B LDS tile -> live set ~40 VGPR, LDS 32.9 KB -> 4 blocks/CU cap.
__global__ __launch_bounds__(512)
void g1mu(const float* __restrict__ x, const _Float16* __restrict__ gwF,
          const float* __restrict__ gb, _Float16* __restrict__ muFg) {
  __shared__ union {
    _Float16 A[32 * LDP];    //  4,608 B
    float P[32 * PSTR];      // 32,896 B
  } sm;

  const int tid  = threadIdx.x;
  const int wave = tid >> 6, lane = tid & 63;
  const int ln15 = lane & 15, lhi = lane >> 4;
  const int wr = wave >> 2, wc = wave & 3;      // 2x4 waves: 16 rows x 64 cols
  const int r0 = blockIdx.x * 32;

  // ---------------- phase 1: logits = x @ W^T ----------------
  f32x4 acc1[4] = {};
  const int arow = tid >> 4, acol = (tid & 15) * 4;  // A: 1 float4/thread

  float4 pa = *(const float4*)&x[(size_t)(r0 + arow) * NFEAT + acol];
  for (int k = 0; k < NFEAT / 64; ++k) {
    {  // write A tile (f32->f16)
      f16x4 h;
      h[0] = (_Float16)pa.x; h[1] = (_Float16)pa.y;
      h[2] = (_Float16)pa.z; h[3] = (_Float16)pa.w;
      *(f16x4*)&sm.A[arow * LDP + acol] = h;
    }
    __syncthreads();
    if (k < NFEAT / 64 - 1)
      pa = *(const float4*)&x[(size_t)(r0 + arow) * NFEAT + (k + 1) * 64 + acol];
#pragma unroll
    for (int kk = 0; kk < 2; ++kk) {
      f16x8 a = *(const f16x8*)&sm.A[(wr * 16 + ln15) * LDP + kk * 32 + lhi * 8];
#pragma unroll
      for (int n = 0; n < 4; ++n) {
        // B fragment straight from L2: 64 lanes x 16B = 1KB contiguous
        f16x8 b = *(const f16x8*)&gwF[(((size_t)(wc * 4 + n) * 16 + k * 2 + kk) * 64 + lane) * 8];
        acc1[n] = __builtin_amdgcn_mfma_f32_16x16x32_f16(a, b, acc1[n], 0, 0, 0);
      }
    }
    __syncthreads();
  }

  // ---------------- phase 2a: sigmoid -> P (LDS, stride 257) ----------------
#pragma unroll
  for (int n = 0; n < 4; ++n) {
    int col = wc * 64 + n * 16 + ln15;
    float bb = (col < NINT) ? gb[col] : 0.f;
#pragma unroll
    for (int j = 0; j < 4; ++j) {
      int rl = wr * 16 + lhi * 4 + j;
      float v = acc1[n][j] + bb;
      sm.P[rl * PSTR + col] = 1.f / (1.f + __expf(-v));
    }
  }
  __syncthreads();

  // ---------------- phase 2b: tree product -> muFg (global, fragment layout) ----------------
  const int lf   = lane * 4;
  const int g_hi = lane >> 3;            // k-tile index (leaf>>5)
  const int sub  = ((lane >> 1) & 3) * 16;
  const int j4   = (lane & 1) * 4;
#pragma unroll
  for (int rr = 0; rr < 4; ++rr) {
    int row = wave * 4 + rr;             // 8 waves x 4 = 32 rows
    const float* p = &sm.P[row * PSTR];
    float pre = 1.f;
#pragma unroll
    for (int d = 0; d < 6; ++d) {
      int node = (1 << d) - 1 + (lf >> (8 - d));
      int bit  = (lf >> (7 - d)) & 1;
      float g = p[node];
      pre *= bit ? g : (1.f - g);
    }
    float g6  = p[63 + lane];
    float g7a = p[127 + 2 * lane];
    float g7b = p[128 + 2 * lane];
    f16x4 o;
    o[0] = (_Float16)(pre * (1.f - g6) * (1.f - g7a));
    o[1] = (_Float16)(pre * (1.f - g6) * g7a);
    o[2] = (_Float16)(pre * g6 * (1.f - g7b));
    o[3] = (_Float16)(pre * g6 * g7b);
    int row_g = r0 + row;
    size_t idx = (((size_t)(row_g >> 4) * 8 + g_hi) * 64 + sub + (row_g & 15)) * 8 + j4;
    *(f16x4*)&muFg[idx] = o;
  }
}

// ---- kernel 2: out = mu @ dist^T. No LDS, fragment loads, high occupancy ----
// grid (256 row-blocks x 4 col-strips), 256 threads (4 waves).
__global__ __launch_bounds__(256)
void g2(const _Float16* __restrict__ muFg, const _Float16* __restrict__ distF,
        float* __restrict__ out) {
  const int tid  = threadIdx.x;
  const int wave = tid >> 6, lane = tid & 63;
  const int ln15 = lane & 15, lhi = lane >> 4;
  const int row16 = blockIdx.x * 4 + wave;     // 16-row group
  const int cs    = blockIdx.y;                // 256-col strip

  f16x8 aa[8];
#pragma unroll
  for (int kk = 0; kk < 8; ++kk)               // 1KB contiguous per load
    aa[kk] = *(const f16x8*)&muFg[(((size_t)row16 * 8 + kk) * 64 + lane) * 8];

  const int rb = row16 * 16 + lhi * 4;
  for (int ct = 0; ct < 16; ++ct) {
    const int c16 = cs * 16 + ct;
    f32x4 acc = {};
#pragma unroll
    for (int kk = 0; kk < 8; ++kk) {
      f16x8 bb = *(const f16x8*)&distF[(((size_t)c16 * 8 + kk) * 64 + lane) * 8];
      acc = __builtin_amdgcn_mfma_f32_16x16x32_f16(aa[kk], bb, acc, 0, 0, 0);
    }
    const int col = c16 * 16 + ln15;
    if (col < NCLS) {
#pragma unroll
      for (int j = 0; j < 4; ++j)
        out[(size_t)(rb + j) * NCLS + col] = acc[j];
    }
  }
}

extern "C" void kernel_launch(void* const* d_in, const int* in_sizes, int n_in,
                              void* d_out, int out_size, void* d_ws, size_t ws_size,
                              hipStream_t stream) {
  const float* x  = (const float*)d_in[0];   // 16384x512
  const float* gw = (const float*)d_in[1];   // 255x512
  const float* gb = (const float*)d_in[2];   // 255
  const float* ll = (const float*)d_in[3];   // 256x1000
  float* out = (float*)d_out;                // 16384x1000
  char* ws = (char*)d_ws;

  _Float16* gwF   = (_Float16*)(ws);             // 262,144 B (fragment layout)
  _Float16* distF = (_Float16*)(ws + 262144);    // 524,288 B (fragment layout)
  _Float16* muFg  = (_Float16*)(ws + 786432);    // 8,388,608 B (fragment layout)

  cvt_gw   <<<256, 64,  0, stream>>>(gw, gwF);
  softmax_t<<<256, 256, 0, stream>>>(ll, distF);
  g1mu     <<<BATCH / 32, 512, 0, stream>>>(x, gwF, gb, muFg);
  g2       <<<dim3(BATCH / 64, 4), 256, 0, stream>>>(muFg, distF, out);
}